// Round 1
// baseline (339.191 us; speedup 1.0000x reference)
//
#include <hip/hip_runtime.h>
#include <hip/hip_bf16.h>
#include <stdint.h>

typedef __bf16 bf16_t;
typedef __bf16 bf16x8 __attribute__((ext_vector_type(8)));
typedef float  f32x4  __attribute__((ext_vector_type(4)));

static constexpr int BB  = 64;     // batch
static constexpr int NN  = 257;    // tokens
static constexpr int CC  = 768;    // channels
static constexpr int HH  = 12;     // heads
static constexpr int M   = BB * NN;   // 16448 rows
static constexpr int NP  = 288;    // padded token count (18*16, 9*32)
static constexpr int KLD = 72;     // K row stride (elems)  -> 144B rows, conflict-friendly
static constexpr int VLD = 296;    // V^T row stride        -> 592B rows, conflict-friendly
static constexpr int PLD = 296;    // P lds row stride
static constexpr int BJT = 20;     // bias jt dim padded (18 used)
static constexpr float QSCALE = 0.125f;  // 64^-0.5

// ---- workspace layout (bytes) ----
static constexpr size_t OFF_XB   = 0;
static constexpr size_t SZ_XB    = (size_t)M * CC * 2;            // x bf16
static constexpr size_t OFF_WQKV = OFF_XB + SZ_XB;
static constexpr size_t SZ_WQKV  = (size_t)3 * CC * CC * 2;       // qkv_w bf16
static constexpr size_t OFF_WPRJ = OFF_WQKV + SZ_WQKV;
static constexpr size_t SZ_WPRJ  = (size_t)CC * CC * 2;           // proj_w bf16
static constexpr size_t OFF_Q    = OFF_WPRJ + SZ_WPRJ;
static constexpr size_t SZ_Q     = (size_t)BB * HH * NP * 64 * 2; // Q  [bh][288][64]
static constexpr size_t OFF_K    = OFF_Q + SZ_Q;
static constexpr size_t SZ_K     = (size_t)BB * HH * NP * KLD * 2;// K  [bh][288][72]
static constexpr size_t OFF_V    = OFF_K + SZ_K;
static constexpr size_t SZ_V     = (size_t)BB * HH * 64 * VLD * 2;// V^T[bh][64][296]
static constexpr size_t OFF_BIAS = OFF_V + SZ_V;
static constexpr size_t SZ_BIAS  = (size_t)HH * NP * 16 * BJT * 4;// bias [h][q][c][jt]
static constexpr size_t OFF_AO   = OFF_BIAS + SZ_BIAS;
static constexpr size_t SZ_AO    = (size_t)M * CC * 2;            // attn out bf16

__device__ __forceinline__ void load_lds16(const bf16_t* g, bf16_t* l) {
  __builtin_amdgcn_global_load_lds(
      (const __attribute__((address_space(1))) uint32_t*)g,
      (__attribute__((address_space(3))) uint32_t*)l, 16, 0, 0);
}

// -------------------- prep: converts + bias gather --------------------
__global__ void prep_kernel(const float* __restrict__ x, const float* __restrict__ qkv_w,
                            const float* __restrict__ proj_w, const float* __restrict__ rpb,
                            const int* __restrict__ rpi,
                            bf16_t* __restrict__ xb, bf16_t* __restrict__ wqkv,
                            bf16_t* __restrict__ wprj, float* __restrict__ biasr) {
  const int NX4  = M * CC / 4;         // float4 units
  const int NW14 = 3 * CC * CC / 4;
  const int NW24 = CC * CC / 4;
  const int NBI  = HH * NP * 16 * BJT; // scalar units
  const int total = NX4 + NW14 + NW24 + NBI;
  for (int u = blockIdx.x * blockDim.x + threadIdx.x; u < total;
       u += gridDim.x * blockDim.x) {
    if (u < NX4) {
      float4 v = ((const float4*)x)[u];
      union { ushort4 us; bf16_t b[4]; } cv;
      cv.b[0] = (bf16_t)v.x; cv.b[1] = (bf16_t)v.y;
      cv.b[2] = (bf16_t)v.z; cv.b[3] = (bf16_t)v.w;
      ((ushort4*)xb)[u] = cv.us;
    } else if (u < NX4 + NW14) {
      int t = u - NX4;
      float4 v = ((const float4*)qkv_w)[t];
      union { ushort4 us; bf16_t b[4]; } cv;
      cv.b[0] = (bf16_t)v.x; cv.b[1] = (bf16_t)v.y;
      cv.b[2] = (bf16_t)v.z; cv.b[3] = (bf16_t)v.w;
      ((ushort4*)wqkv)[t] = cv.us;
    } else if (u < NX4 + NW14 + NW24) {
      int t = u - NX4 - NW14;
      float4 v = ((const float4*)proj_w)[t];
      union { ushort4 us; bf16_t b[4]; } cv;
      cv.b[0] = (bf16_t)v.x; cv.b[1] = (bf16_t)v.y;
      cv.b[2] = (bf16_t)v.z; cv.b[3] = (bf16_t)v.w;
      ((ushort4*)wprj)[t] = cv.us;
    } else {
      int t  = u - NX4 - NW14 - NW24;
      int jt = t % BJT;
      int c  = (t / BJT) & 15;
      int q  = (t / (BJT * 16)) % NP;
      int h  = t / (BJT * 16 * NP);
      int key = jt * 16 + c;
      float val;
      if (key < NN && q < NN) val = rpb[rpi[q * NN + key] * HH + h];
      else                    val = (key >= NN) ? -1e30f : 0.0f;
      biasr[t] = val;
    }
  }
}

// -------------------- GEMM (m97 structure), 2 epilogues --------------------
// C[m][n] = sum_k A[m][k] * Bt[n][k].   MODE 0: qkv epilogue, MODE 1: proj.
template <int MODE>
__global__ __launch_bounds__(256) void gemm_kernel(
    const bf16_t* __restrict__ A, const bf16_t* __restrict__ Bt,
    const float* __restrict__ bias0, const float* __restrict__ bias1,
    bf16_t* __restrict__ qo, bf16_t* __restrict__ ko, bf16_t* __restrict__ vo,
    float* __restrict__ fo) {
  __shared__ bf16_t Alds[128 * 64];
  __shared__ bf16_t Blds[128 * 64];
  const int tn = blockIdx.x, tm = blockIdx.y;
  const int tid = threadIdx.x;
  const int w = tid >> 6, lane = tid & 63;
  const int wm = w >> 1, wn = w & 1;
  const int g = lane >> 4, cq = lane & 15;
  const int lrow = lane >> 3;        // 0..7 within 8-row chunk
  const int lcol = (lane & 7) * 8;   // elem col within 64
  f32x4 acc[4][4] = {};

  for (int kt = 0; kt < 12; ++kt) {
    __syncthreads();
#pragma unroll
    for (int i = 0; i < 4; ++i) {
      int chunk = w * 4 + i;
      int arow = tm * 128 + chunk * 8 + lrow;
      arow = (arow < M) ? arow : (M - 1);   // clamp last tile
      load_lds16(A + (size_t)arow * CC + kt * 64 + lcol, &Alds[chunk * 512]);
      int brow = tn * 128 + chunk * 8 + lrow;
      load_lds16(Bt + (size_t)brow * CC + kt * 64 + lcol, &Blds[chunk * 512]);
    }
    __syncthreads();
#pragma unroll
    for (int ks = 0; ks < 2; ++ks) {
      bf16x8 af[4], bfr[4];
#pragma unroll
      for (int mi = 0; mi < 4; ++mi)
        af[mi] = *(const bf16x8*)&Alds[(wm * 64 + mi * 16 + cq) * 64 + ks * 32 + 8 * g];
#pragma unroll
      for (int ni = 0; ni < 4; ++ni)
        bfr[ni] = *(const bf16x8*)&Blds[(wn * 64 + ni * 16 + cq) * 64 + ks * 32 + 8 * g];
#pragma unroll
      for (int mi = 0; mi < 4; ++mi)
#pragma unroll
        for (int ni = 0; ni < 4; ++ni)
          acc[mi][ni] = __builtin_amdgcn_mfma_f32_16x16x32_bf16(
              af[mi], bfr[ni], acc[mi][ni], 0, 0, 0);
    }
  }

#pragma unroll
  for (int mi = 0; mi < 4; ++mi) {
#pragma unroll
    for (int r = 0; r < 4; ++r) {
      int m = tm * 128 + wm * 64 + mi * 16 + 4 * g + r;
      if (m >= M) continue;
      int bidx = m / NN, nn = m % NN;
#pragma unroll
      for (int ni = 0; ni < 4; ++ni) {
        int cg = tn * 128 + wn * 64 + ni * 16 + cq;
        float v = acc[mi][ni][r];
        if (MODE == 0) {
          if (cg < CC) {                       // Q (+bias, *scale)
            int h = cg >> 6, hd = cg & 63;
            qo[((size_t)(bidx * HH + h) * NP + nn) * 64 + hd] =
                (bf16_t)((v + bias0[cg]) * QSCALE);
          } else if (cg < 2 * CC) {            // K (no bias)
            int c2 = cg - CC; int h = c2 >> 6, hd = c2 & 63;
            ko[((size_t)(bidx * HH + h) * NP + nn) * KLD + hd] = (bf16_t)v;
          } else {                             // V^T (+bias)
            int c2 = cg - 2 * CC; int h = c2 >> 6, hd = c2 & 63;
            vo[((size_t)(bidx * HH + h) * 64 + hd) * VLD + nn] =
                (bf16_t)(v + bias1[c2]);
          }
        } else {
          fo[(size_t)m * CC + cg] = v + bias0[cg];
        }
      }
    }
  }
}

// -------------------- attention: one block per (b,h) --------------------
__global__ __launch_bounds__(256) void attn_kernel(
    const bf16_t* __restrict__ qg, const bf16_t* __restrict__ kg,
    const bf16_t* __restrict__ vg, const float* __restrict__ biasr,
    bf16_t* __restrict__ outb) {
  __shared__ bf16_t Pbuf[4][16 * PLD];
  const int bh = blockIdx.x;
  const int b = bh / HH, h = bh % HH;
  const int w = threadIdx.x >> 6, lane = threadIdx.x & 63;
  const int g = lane >> 4, cq = lane & 15;
  const bf16_t* qp = qg + (size_t)bh * NP * 64;
  const bf16_t* kp = kg + (size_t)bh * NP * KLD;
  const bf16_t* vp = vg + (size_t)bh * 64 * VLD;
  const float*  bp = biasr + (size_t)h * NP * 16 * BJT;
  bf16_t* pl = &Pbuf[w][0];

  for (int qt = w; qt < 17; qt += 4) {   // 17 tiles cover 272 >= 257 rows
    // Q fragments (rows = qt*16 + cq)
    bf16x8 aq0 = *(const bf16x8*)&qp[(qt * 16 + cq) * 64 + 8 * g];
    bf16x8 aq1 = *(const bf16x8*)&qp[(qt * 16 + cq) * 64 + 32 + 8 * g];

    // init S with rel-pos bias (MFMA C-in); masked keys get -1e30
    f32x4 s[18];
#pragma unroll
    for (int r = 0; r < 4; ++r) {
      const f32x4* bb = (const f32x4*)&bp[((qt * 16 + 4 * g + r) * 16 + cq) * BJT];
      f32x4 bv[5];
#pragma unroll
      for (int i = 0; i < 5; ++i) bv[i] = bb[i];
#pragma unroll
      for (int jt = 0; jt < 18; ++jt) s[jt][r] = bv[jt >> 2][jt & 3];
    }

    // S += Q K^T
#pragma unroll
    for (int jt = 0; jt < 18; ++jt) {
      bf16x8 kb0 = *(const bf16x8*)&kp[(jt * 16 + cq) * KLD + 8 * g];
      bf16x8 kb1 = *(const bf16x8*)&kp[(jt * 16 + cq) * KLD + 32 + 8 * g];
      s[jt] = __builtin_amdgcn_mfma_f32_16x16x32_bf16(aq0, kb0, s[jt], 0, 0, 0);
      s[jt] = __builtin_amdgcn_mfma_f32_16x16x32_bf16(aq1, kb1, s[jt], 0, 0, 0);
    }

    // masked softmax, rows live across (g, r); cols across cq x jt
    float inv[4];
#pragma unroll
    for (int r = 0; r < 4; ++r) {
      float mx = s[0][r];
#pragma unroll
      for (int jt = 1; jt < 18; ++jt) mx = fmaxf(mx, s[jt][r]);
      mx = fmaxf(mx, __shfl_xor(mx, 1, 16));
      mx = fmaxf(mx, __shfl_xor(mx, 2, 16));
      mx = fmaxf(mx, __shfl_xor(mx, 4, 16));
      mx = fmaxf(mx, __shfl_xor(mx, 8, 16));
      float sum = 0.f;
#pragma unroll
      for (int jt = 0; jt < 18; ++jt) {
        float e = __expf(s[jt][r] - mx);
        s[jt][r] = e;
        sum += e;
      }
      sum += __shfl_xor(sum, 1, 16);
      sum += __shfl_xor(sum, 2, 16);
      sum += __shfl_xor(sum, 4, 16);
      sum += __shfl_xor(sum, 8, 16);
      inv[r] = 1.0f / sum;
    }

    // P -> per-wave LDS slab (bf16), rows 0..15, cols 0..287
#pragma unroll
    for (int jt = 0; jt < 18; ++jt)
#pragma unroll
      for (int r = 0; r < 4; ++r)
        pl[(4 * g + r) * PLD + jt * 16 + cq] = (bf16_t)s[jt][r];
    __asm__ volatile("s_waitcnt lgkmcnt(0)" ::: "memory");
    __builtin_amdgcn_sched_barrier(0);

    // O = P V  (V^T streamed from L2)
    f32x4 o[4] = {};
#pragma unroll
    for (int kk = 0; kk < 9; ++kk) {
      bf16x8 pa = *(const bf16x8*)&pl[cq * PLD + kk * 32 + 8 * g];
#pragma unroll
      for (int nt = 0; nt < 4; ++nt) {
        bf16x8 vb = *(const bf16x8*)&vp[(nt * 16 + cq) * VLD + kk * 32 + 8 * g];
        o[nt] = __builtin_amdgcn_mfma_f32_16x16x32_bf16(pa, vb, o[nt], 0, 0, 0);
      }
    }

    // epilogue: divide by row-sum, store bf16 [b*257+q][h*64+hd]
#pragma unroll
    for (int r = 0; r < 4; ++r) {
      int q = qt * 16 + 4 * g + r;
      if (q < NN) {
        float iv = inv[r];
#pragma unroll
        for (int nt = 0; nt < 4; ++nt)
          outb[((size_t)b * NN + q) * CC + h * 64 + nt * 16 + cq] =
              (bf16_t)(o[nt][r] * iv);
      }
    }
  }
}

// -------------------- launch --------------------
extern "C" void kernel_launch(void* const* d_in, const int* in_sizes, int n_in,
                              void* d_out, int out_size, void* d_ws, size_t ws_size,
                              hipStream_t stream) {
  const float* x      = (const float*)d_in[0];
  const float* qkv_w  = (const float*)d_in[1];
  const float* q_bias = (const float*)d_in[2];
  const float* v_bias = (const float*)d_in[3];
  const float* rpb    = (const float*)d_in[4];
  const float* proj_w = (const float*)d_in[5];
  const float* proj_b = (const float*)d_in[6];
  const int*   rpi    = (const int*)d_in[7];

  char* ws = (char*)d_ws;
  bf16_t* xb    = (bf16_t*)(ws + OFF_XB);
  bf16_t* wqkv  = (bf16_t*)(ws + OFF_WQKV);
  bf16_t* wprj  = (bf16_t*)(ws + OFF_WPRJ);
  bf16_t* qo    = (bf16_t*)(ws + OFF_Q);
  bf16_t* ko    = (bf16_t*)(ws + OFF_K);
  bf16_t* vo    = (bf16_t*)(ws + OFF_V);
  float*  biasr = (float*)(ws + OFF_BIAS);
  bf16_t* ao    = (bf16_t*)(ws + OFF_AO);
  float*  out   = (float*)d_out;

  // zero Q/K/V slabs so pad rows/cols are 0 every call (poison-safe)
  hipMemsetAsync(ws + OFF_Q, 0, SZ_Q + SZ_K + SZ_V, stream);
  prep_kernel<<<2048, 256, 0, stream>>>(x, qkv_w, proj_w, rpb, rpi, xb, wqkv, wprj, biasr);
  gemm_kernel<0><<<dim3(18, 129), 256, 0, stream>>>(xb, wqkv, q_bias, v_bias,
                                                    qo, ko, vo, nullptr);
  attn_kernel<<<768, 256, 0, stream>>>(qo, ko, vo, biasr, ao);
  gemm_kernel<1><<<dim3(6, 129), 256, 0, stream>>>(ao, wprj, proj_b, nullptr,
                                                   nullptr, nullptr, nullptr, out);
}

// Round 2
// 331.197 us; speedup vs baseline: 1.0241x; 1.0241x over previous
//
#include <hip/hip_runtime.h>
#include <hip/hip_bf16.h>
#include <stdint.h>

typedef __bf16 bf16_t;
typedef __bf16 bf16x8 __attribute__((ext_vector_type(8)));
typedef float  f32x4  __attribute__((ext_vector_type(4)));

static constexpr int BB  = 64;     // batch
static constexpr int NN  = 257;    // tokens
static constexpr int CC  = 768;    // channels
static constexpr int HH  = 12;     // heads
static constexpr int M   = BB * NN;   // 16448 rows
static constexpr int NP  = 288;    // padded token count
static constexpr int KLD = 72;     // K row stride (elems)
static constexpr int VLD = 296;    // V^T row stride
static constexpr int PLD = 296;    // P lds row stride
static constexpr int BJT = 20;     // bias jt dim padded (18 used)
static constexpr int KT  = CC / 64;   // 12 K-tiles of 64
static constexpr float QSCALE = 0.125f;

// ---- workspace layout (bytes) ----
static constexpr size_t OFF_XB   = 0;
static constexpr size_t SZ_XB    = (size_t)M * CC * 2;
static constexpr size_t OFF_WQKV = OFF_XB + SZ_XB;
static constexpr size_t SZ_WQKV  = (size_t)3 * CC * CC * 2;
static constexpr size_t OFF_WPRJ = OFF_WQKV + SZ_WQKV;
static constexpr size_t SZ_WPRJ  = (size_t)CC * CC * 2;
static constexpr size_t OFF_Q    = OFF_WPRJ + SZ_WPRJ;
static constexpr size_t SZ_Q     = (size_t)BB * HH * NP * 64 * 2;
static constexpr size_t OFF_K    = OFF_Q + SZ_Q;
static constexpr size_t SZ_K     = (size_t)BB * HH * NP * KLD * 2;
static constexpr size_t OFF_V    = OFF_K + SZ_K;
static constexpr size_t SZ_V     = (size_t)BB * HH * 64 * VLD * 2;
static constexpr size_t OFF_BIAS = OFF_V + SZ_V;
static constexpr size_t SZ_BIAS  = (size_t)HH * NP * 16 * BJT * 4;
static constexpr size_t OFF_AO   = OFF_BIAS + SZ_BIAS;
static constexpr size_t SZ_AO    = (size_t)M * CC * 2;

__device__ __forceinline__ void load_lds16(const bf16_t* g, bf16_t* l) {
  __builtin_amdgcn_global_load_lds(
      (const __attribute__((address_space(1))) uint32_t*)g,
      (__attribute__((address_space(3))) uint32_t*)l, 16, 0, 0);
}

#define BARRIER()    asm volatile("s_barrier" ::: "memory")
#define WAIT_LGKM0() asm volatile("s_waitcnt lgkmcnt(0)" ::: "memory")
#define WAIT_VM6()   asm volatile("s_waitcnt vmcnt(6)" ::: "memory")
#define WAIT_VM4()   asm volatile("s_waitcnt vmcnt(4)" ::: "memory")
#define WAIT_VM0()   asm volatile("s_waitcnt vmcnt(0)" ::: "memory")

// -------------------- prep: converts + bias gather + K/V pad zero ------------
__global__ void prep_kernel(const float* __restrict__ x, const float* __restrict__ qkv_w,
                            const float* __restrict__ proj_w, const float* __restrict__ rpb,
                            const int* __restrict__ rpi,
                            bf16_t* __restrict__ xb, bf16_t* __restrict__ wqkv,
                            bf16_t* __restrict__ wprj, float* __restrict__ biasr,
                            bf16_t* __restrict__ kz, bf16_t* __restrict__ vz) {
  const int NX4  = M * CC / 4;
  const int NW14 = 3 * CC * CC / 4;
  const int NW24 = CC * CC / 4;
  const int NBI  = HH * NP * 16 * BJT;
  const int NPK  = BB * HH * 31 * KLD;   // K pad rows 257..287
  const int NPV  = BB * HH * 64 * 39;    // V^T pad cols 257..295
  const int total = NX4 + NW14 + NW24 + NBI + NPK + NPV;
  for (int u = blockIdx.x * blockDim.x + threadIdx.x; u < total;
       u += gridDim.x * blockDim.x) {
    if (u < NX4) {
      float4 v = ((const float4*)x)[u];
      union { ushort4 us; bf16_t b[4]; } cv;
      cv.b[0] = (bf16_t)v.x; cv.b[1] = (bf16_t)v.y;
      cv.b[2] = (bf16_t)v.z; cv.b[3] = (bf16_t)v.w;
      ((ushort4*)xb)[u] = cv.us;
    } else if (u < NX4 + NW14) {
      int t = u - NX4;
      float4 v = ((const float4*)qkv_w)[t];
      union { ushort4 us; bf16_t b[4]; } cv;
      cv.b[0] = (bf16_t)v.x; cv.b[1] = (bf16_t)v.y;
      cv.b[2] = (bf16_t)v.z; cv.b[3] = (bf16_t)v.w;
      ((ushort4*)wqkv)[t] = cv.us;
    } else if (u < NX4 + NW14 + NW24) {
      int t = u - NX4 - NW14;
      float4 v = ((const float4*)proj_w)[t];
      union { ushort4 us; bf16_t b[4]; } cv;
      cv.b[0] = (bf16_t)v.x; cv.b[1] = (bf16_t)v.y;
      cv.b[2] = (bf16_t)v.z; cv.b[3] = (bf16_t)v.w;
      ((ushort4*)wprj)[t] = cv.us;
    } else if (u < NX4 + NW14 + NW24 + NBI) {
      int t  = u - NX4 - NW14 - NW24;
      int jt = t % BJT;
      int c  = (t / BJT) & 15;
      int q  = (t / (BJT * 16)) % NP;
      int h  = t / (BJT * 16 * NP);
      int key = jt * 16 + c;
      float val;
      if (key < NN && q < NN) val = rpb[rpi[q * NN + key] * HH + h];
      else                    val = (key >= NN) ? -1e30f : 0.0f;
      biasr[t] = val;
    } else if (u < NX4 + NW14 + NW24 + NBI + NPK) {
      int t = u - NX4 - NW14 - NW24 - NBI;
      int c = t % KLD;
      int r = (t / KLD) % 31;
      int bh = t / (KLD * 31);
      kz[((size_t)bh * NP + 257 + r) * KLD + c] = (bf16_t)0.0f;
    } else {
      int t = u - NX4 - NW14 - NW24 - NBI - NPK;
      int c = t % 39;
      int rf = t / 39;   // bh*64 + hd
      vz[(size_t)rf * VLD + 257 + c] = (bf16_t)0.0f;
    }
  }
}

// -------------------- 256x256 8-phase GEMM (T1+T2+T3+T4+T5) ------------------
// C[m][n] = sum_k A[m][k]*Bt[n][k].  MODE 0: QKV scatter epilogue, 1: proj.
// 512 threads = 8 waves (2M x 4N), BK=64, 2-slot dbuf LDS with XOR swizzle.
template <int MODE>
__global__ __launch_bounds__(512, 2) void gemm8_kernel(
    const bf16_t* __restrict__ A, const bf16_t* __restrict__ Bt,
    const float* __restrict__ bias0, const float* __restrict__ bias1,
    bf16_t* __restrict__ qo, bf16_t* __restrict__ ko, bf16_t* __restrict__ vo,
    float* __restrict__ fo, int gn) {
  __shared__ bf16_t lds[2][2][256 * 64];   // [slot][A|B][row*64 + col], swizzled

  // T1: bijective XCD swizzle
  const int nwg = gridDim.x, orig = blockIdx.x;
  const int qq = nwg >> 3, rr8 = nwg & 7;
  const int xcd = orig & 7, local = orig >> 3;
  const int wg = (xcd < rr8 ? xcd * (qq + 1) : rr8 * (qq + 1) + (xcd - rr8) * qq) + local;
  const int tm = wg / gn, tn = wg % gn;
  const int tmBase = tm * 256, tnBase = tn * 256;

  const int tid = threadIdx.x;
  const int w = tid >> 6, lane = tid & 63;
  const int wm = w >> 2, wn = w & 3;       // wave tile: rows wm*128, cols wn*64
  const int g = lane >> 4, cq = lane & 15;
  const int gx = (8 * g) ^ (((cq >> 2) & 3) << 3);   // swizzled frag col base

  // stage one half-tile (128 rows x 64 cols) : 2 x global_load_lds per thread
  auto stage_half = [&](const bf16_t* __restrict__ gsrc, int grBase, int grMax,
                        int kcol, bf16_t* ldsHalf) {
#pragma unroll
    for (int j = 0; j < 2; ++j) {
      int r = (j * 8 + w) * 8 + (lane >> 3);
      int c = ((lane & 7) * 8) ^ (((r >> 2) & 3) << 3);   // inverse-swizzled src
      int gr = grBase + r; gr = gr < grMax ? gr : grMax - 1;
      load_lds16(gsrc + (size_t)gr * CC + kcol + c, ldsHalf + (j * 8 + w) * 512);
    }
  };
  // issue half-tile #seq of the global sequence (4 per K-tile: Ah0,Ah1,Bh0,Bh1)
  auto ISSUE = [&](int seq) {
    int kth = seq >> 2;
    if (kth >= KT) return;
    int part = seq & 3, slot = kth & 1;
    if (part < 2)
      stage_half(A, tmBase + part * 128, M, kth * 64, &lds[slot][0][part * 8192]);
    else
      stage_half(Bt, tnBase + (part - 2) * 128, 1 << 30, kth * 64,
                 &lds[slot][1][(part - 2) * 8192]);
  };

  f32x4 acc[8][4] = {};

#define READ_A4(MB) do { \
  _Pragma("unroll") for (int mi2 = 0; mi2 < 4; ++mi2) \
  _Pragma("unroll") for (int ks = 0; ks < 2; ++ks) \
    af[(MB) + mi2][ks] = *(const bf16x8*)&At[(wm * 128 + ((MB) + mi2) * 16 + cq) * 64 + ks * 32 + gx]; \
} while (0)
#define READ_B2(NB) do { \
  _Pragma("unroll") for (int ni2 = 0; ni2 < 2; ++ni2) \
  _Pragma("unroll") for (int ks = 0; ks < 2; ++ks) \
    bfr[(NB) + ni2][ks] = *(const bf16x8*)&Bl[(wn * 64 + ((NB) + ni2) * 16 + cq) * 64 + ks * 32 + gx]; \
} while (0)
#define MFMA_Q(MB, NB) do { \
  __builtin_amdgcn_s_setprio(1); \
  _Pragma("unroll") for (int mi2 = 0; mi2 < 4; ++mi2) \
  _Pragma("unroll") for (int ni2 = 0; ni2 < 2; ++ni2) \
  _Pragma("unroll") for (int ks = 0; ks < 2; ++ks) \
    acc[(MB) + mi2][(NB) + ni2] = __builtin_amdgcn_mfma_f32_16x16x32_bf16( \
        af[(MB) + mi2][ks], bfr[(NB) + ni2][ks], acc[(MB) + mi2][(NB) + ni2], 0, 0, 0); \
  __builtin_amdgcn_s_setprio(0); \
} while (0)

  // prologue: kt0 fully, kt1 3 halves; drain so kt0 is resident
  ISSUE(0); ISSUE(1); ISSUE(2); ISSUE(3);
  WAIT_VM4();
  ISSUE(4); ISSUE(5); ISSUE(6);
  WAIT_VM6();
  BARRIER();

  for (int kt = 0; kt < KT; ++kt) {
    const bf16_t* At = lds[kt & 1][0];
    const bf16_t* Bl = lds[kt & 1][1];
    bf16x8 af[8][2], bfr[4][2];
    // phase 1: 12 ds_reads, stage, Q0
    READ_A4(0); READ_B2(0);
    ISSUE(kt * 4 + 7);
    BARRIER(); WAIT_LGKM0(); __builtin_amdgcn_sched_barrier(0);
    MFMA_Q(0, 0);
    BARRIER();
    // phase 2: 8 ds_reads, stage, Q1
    READ_A4(4);
    ISSUE(kt * 4 + 8);
    BARRIER(); WAIT_LGKM0(); __builtin_amdgcn_sched_barrier(0);
    MFMA_Q(4, 0);
    BARRIER();
    // phase 3: 4 ds_reads, stage, Q2
    READ_B2(2);
    ISSUE(kt * 4 + 9);
    BARRIER(); WAIT_LGKM0(); __builtin_amdgcn_sched_barrier(0);
    MFMA_Q(0, 2);
    BARRIER();
    // phase 4: stage, Q3, counted vmcnt (next K-tile resident), barrier
    ISSUE(kt * 4 + 10);
    BARRIER();
    MFMA_Q(4, 2);
    if (kt < KT - 2) { WAIT_VM6(); }
    else if (kt == KT - 2) { WAIT_VM0(); }
    BARRIER();
  }
#undef READ_A4
#undef READ_B2
#undef MFMA_Q

  // epilogue
#pragma unroll
  for (int mi = 0; mi < 8; ++mi) {
#pragma unroll
    for (int r = 0; r < 4; ++r) {
      int m = tmBase + wm * 128 + mi * 16 + 4 * g + r;
      if (m >= M) continue;
      int bidx = m / NN, nn = m % NN;
#pragma unroll
      for (int ni = 0; ni < 4; ++ni) {
        int cg = tnBase + wn * 64 + ni * 16 + cq;
        float v = acc[mi][ni][r];
        if (MODE == 0) {
          if (cg < CC) {                       // Q (+bias, *scale)
            int h = cg >> 6, hd = cg & 63;
            qo[((size_t)(bidx * HH + h) * NP + nn) * 64 + hd] =
                (bf16_t)((v + bias0[cg]) * QSCALE);
          } else if (cg < 2 * CC) {            // K
            int c2 = cg - CC; int h = c2 >> 6, hd = c2 & 63;
            ko[((size_t)(bidx * HH + h) * NP + nn) * KLD + hd] = (bf16_t)v;
          } else {                             // V^T (+bias)
            int c2 = cg - 2 * CC; int h = c2 >> 6, hd = c2 & 63;
            vo[((size_t)(bidx * HH + h) * 64 + hd) * VLD + nn] =
                (bf16_t)(v + bias1[c2]);
          }
        } else {
          fo[(size_t)m * CC + cg] = v + bias0[cg];
        }
      }
    }
  }
}

// -------------------- attention: one block per (b,h) --------------------
__global__ __launch_bounds__(256) void attn_kernel(
    const bf16_t* __restrict__ qg, const bf16_t* __restrict__ kg,
    const bf16_t* __restrict__ vg, const float* __restrict__ biasr,
    bf16_t* __restrict__ outb) {
  __shared__ bf16_t Pbuf[4][16 * PLD];
  const int bh = blockIdx.x;
  const int b = bh / HH, h = bh % HH;
  const int w = threadIdx.x >> 6, lane = threadIdx.x & 63;
  const int g = lane >> 4, cq = lane & 15;
  const bf16_t* qp = qg + (size_t)bh * NP * 64;
  const bf16_t* kp = kg + (size_t)bh * NP * KLD;
  const bf16_t* vp = vg + (size_t)bh * 64 * VLD;
  const float*  bp = biasr + (size_t)h * NP * 16 * BJT;
  bf16_t* pl = &Pbuf[w][0];

  for (int qt = w; qt < 17; qt += 4) {
    bf16x8 aq0 = *(const bf16x8*)&qp[(qt * 16 + cq) * 64 + 8 * g];
    bf16x8 aq1 = *(const bf16x8*)&qp[(qt * 16 + cq) * 64 + 32 + 8 * g];

    f32x4 s[18];
#pragma unroll
    for (int r = 0; r < 4; ++r) {
      const f32x4* bb = (const f32x4*)&bp[((qt * 16 + 4 * g + r) * 16 + cq) * BJT];
      f32x4 bv[5];
#pragma unroll
      for (int i = 0; i < 5; ++i) bv[i] = bb[i];
#pragma unroll
      for (int jt = 0; jt < 18; ++jt) s[jt][r] = bv[jt >> 2][jt & 3];
    }

#pragma unroll
    for (int jt = 0; jt < 18; ++jt) {
      bf16x8 kb0 = *(const bf16x8*)&kp[(jt * 16 + cq) * KLD + 8 * g];
      bf16x8 kb1 = *(const bf16x8*)&kp[(jt * 16 + cq) * KLD + 32 + 8 * g];
      s[jt] = __builtin_amdgcn_mfma_f32_16x16x32_bf16(aq0, kb0, s[jt], 0, 0, 0);
      s[jt] = __builtin_amdgcn_mfma_f32_16x16x32_bf16(aq1, kb1, s[jt], 0, 0, 0);
    }

    float inv[4];
#pragma unroll
    for (int r = 0; r < 4; ++r) {
      float mx = s[0][r];
#pragma unroll
      for (int jt = 1; jt < 18; ++jt) mx = fmaxf(mx, s[jt][r]);
      mx = fmaxf(mx, __shfl_xor(mx, 1, 16));
      mx = fmaxf(mx, __shfl_xor(mx, 2, 16));
      mx = fmaxf(mx, __shfl_xor(mx, 4, 16));
      mx = fmaxf(mx, __shfl_xor(mx, 8, 16));
      float sum = 0.f;
#pragma unroll
      for (int jt = 0; jt < 18; ++jt) {
        float e = __expf(s[jt][r] - mx);
        s[jt][r] = e;
        sum += e;
      }
      sum += __shfl_xor(sum, 1, 16);
      sum += __shfl_xor(sum, 2, 16);
      sum += __shfl_xor(sum, 4, 16);
      sum += __shfl_xor(sum, 8, 16);
      inv[r] = 1.0f / sum;
    }

#pragma unroll
    for (int jt = 0; jt < 18; ++jt)
#pragma unroll
      for (int r = 0; r < 4; ++r)
        pl[(4 * g + r) * PLD + jt * 16 + cq] = (bf16_t)s[jt][r];
    __asm__ volatile("s_waitcnt lgkmcnt(0)" ::: "memory");
    __builtin_amdgcn_sched_barrier(0);

    f32x4 o[4] = {};
#pragma unroll
    for (int kk = 0; kk < 9; ++kk) {
      bf16x8 pa = *(const bf16x8*)&pl[cq * PLD + kk * 32 + 8 * g];
#pragma unroll
      for (int nt = 0; nt < 4; ++nt) {
        bf16x8 vb = *(const bf16x8*)&vp[(nt * 16 + cq) * VLD + kk * 32 + 8 * g];
        o[nt] = __builtin_amdgcn_mfma_f32_16x16x32_bf16(pa, vb, o[nt], 0, 0, 0);
      }
    }

#pragma unroll
    for (int r = 0; r < 4; ++r) {
      int q = qt * 16 + 4 * g + r;
      if (q < NN) {
        float iv = inv[r];
#pragma unroll
        for (int nt = 0; nt < 4; ++nt)
          outb[((size_t)b * NN + q) * CC + h * 64 + nt * 16 + cq] =
              (bf16_t)(o[nt][r] * iv);
      }
    }
  }
}

// -------------------- launch --------------------
extern "C" void kernel_launch(void* const* d_in, const int* in_sizes, int n_in,
                              void* d_out, int out_size, void* d_ws, size_t ws_size,
                              hipStream_t stream) {
  const float* x      = (const float*)d_in[0];
  const float* qkv_w  = (const float*)d_in[1];
  const float* q_bias = (const float*)d_in[2];
  const float* v_bias = (const float*)d_in[3];
  const float* rpb    = (const float*)d_in[4];
  const float* proj_w = (const float*)d_in[5];
  const float* proj_b = (const float*)d_in[6];
  const int*   rpi    = (const int*)d_in[7];

  char* ws = (char*)d_ws;
  bf16_t* xb    = (bf16_t*)(ws + OFF_XB);
  bf16_t* wqkv  = (bf16_t*)(ws + OFF_WQKV);
  bf16_t* wprj  = (bf16_t*)(ws + OFF_WPRJ);
  bf16_t* qo    = (bf16_t*)(ws + OFF_Q);
  bf16_t* ko    = (bf16_t*)(ws + OFF_K);
  bf16_t* vo    = (bf16_t*)(ws + OFF_V);
  float*  biasr = (float*)(ws + OFF_BIAS);
  bf16_t* ao    = (bf16_t*)(ws + OFF_AO);
  float*  out   = (float*)d_out;

  prep_kernel<<<2048, 256, 0, stream>>>(x, qkv_w, proj_w, rpb, rpi,
                                        xb, wqkv, wprj, biasr, ko, vo);
  gemm8_kernel<0><<<65 * 9, 512, 0, stream>>>(xb, wqkv, q_bias, v_bias,
                                              qo, ko, vo, nullptr, 9);
  attn_kernel<<<768, 256, 0, stream>>>(qo, ko, vo, biasr, ao);
  gemm8_kernel<1><<<65 * 3, 512, 0, stream>>>(ao, wprj, proj_b, nullptr,
                                              nullptr, nullptr, nullptr, out, 3);
}